// Round 6
// baseline (503.616 us; speedup 1.0000x reference)
//
#include <hip/hip_runtime.h>
#include <cstdint>

// ---------- common helpers ----------

typedef __bf16 bf16x8 __attribute__((ext_vector_type(8)));
typedef float  f32x4  __attribute__((ext_vector_type(4)));
typedef unsigned short u16x8 __attribute__((ext_vector_type(8)));

__device__ __forceinline__ unsigned short f2b(float f) {
    union { float f; unsigned u; } v; v.f = f;
    unsigned r = v.u + 0x7FFFu + ((v.u >> 16) & 1u);   // RNE
    return (unsigned short)(r >> 16);
}

__device__ __forceinline__ float b2f(unsigned short u) {
    union { unsigned u; float f; } v; v.u = ((unsigned)u) << 16;
    return v.f;
}

__device__ __forceinline__ float fast_tanh(float x) {
    // tanh(x) = 1 - 2/(e^{2x}+1); e^{2x} = 2^(x*2*log2 e). err ~1e-6 << bf16 eps
    float e = __builtin_amdgcn_exp2f(2.885390082f * x);
    return 1.0f - 2.0f * __builtin_amdgcn_rcpf(e + 1.0f);
}

__device__ __forceinline__ void async_copy16(void* lds, const void* g) {
    __builtin_amdgcn_global_load_lds(
        (const __attribute__((address_space(1))) unsigned int*)g,
        (__attribute__((address_space(3))) unsigned int*)lds,
        16, 0, 0);
}

// LDS layout (BK=64): tile rows x 64 bf16; slot q (linear 16B chunks) holds
// global chunk (r=q>>3, c=(q&7)^(r&7)).
// => global chunk (r,c) lives at elem offset r*64 + ((c^(r&7))<<3).
// Staging always writes LDS LINEARLY (slot q at q*16B: lane-consecutive, no
// write conflicts; matches global_load_lds semantics) and pre-swizzles the
// SOURCE column: c_src = (q&7)^(r&7).
// ds_read banks: addr/4 = 32r + 4(c^(r&7)) -> 2-way max (free, m136).

// ---------- conversion kernels ----------

// in: [R][C] fp32 row-major  ->  out: [C][R] bf16 (transposed)
__global__ __launch_bounds__(256) void k_transpose_cvt(const float* __restrict__ in,
                                                       unsigned short* __restrict__ out,
                                                       int R, int C) {
    __shared__ float tile[32][33];
    int bc = blockIdx.x * 32;
    int br = blockIdx.y * 32;
    int tx = threadIdx.x, ty = threadIdx.y;   // (32, 8)
    #pragma unroll
    for (int i = 0; i < 32; i += 8)
        tile[ty + i][tx] = in[(size_t)(br + ty + i) * C + bc + tx];
    __syncthreads();
    #pragma unroll
    for (int i = 0; i < 32; i += 8)
        out[(size_t)(bc + ty + i) * R + br + tx] = f2b(tile[tx][ty + i]);
}

// ---------- GEMM1: 512-thread 128x128 tile, BK=64, bias+tanh -> bf16 ----------
// XCD-swizzled 1-D grid: bm % 8 == xcd. 8 waves, wave tile 64x32.
// A is read DIRECTLY from fp32 x (reg-staged: 2 float4 loads + f2b + linear
// ds_write_b128) -- eliminates the separate x->bf16 conversion pass entirely.
// B staged via global_load_lds (pre-swizzled source).

__global__ __launch_bounds__(512, 3)
void k_gemm_tanh(const float* __restrict__ X,
                 const unsigned short* __restrict__ B,
                 const float* __restrict__ bias,
                 unsigned short* __restrict__ Out, int ldout,
                 int ldx, int ldb, int k_len) {
    __shared__ __align__(16) unsigned short As[128 * 64];
    __shared__ __align__(16) unsigned short Bs[128 * 64];

    const int tid  = threadIdx.x;
    const int wave = tid >> 6;      // 0..7
    const int lane = tid & 63;
    const int quad = lane >> 4;
    const int l16  = lane & 15;
    const int wr   = wave >> 2;     // 0..1 : 64-row half
    const int wc   = wave & 3;      // 0..3 : 32-col quarter

    const int bid = blockIdx.x;
    const int xcd = bid & 7;
    const int lid = bid >> 3;
    const int bn  = lid & 7;
    const int bm  = (lid >> 3) * 8 + xcd;

    const float*          Xg = X + (size_t)(bm * 128) * ldx;
    const unsigned short* Bg = B + (size_t)(bn * 128) * ldb;

    f32x4 acc[4][2];
    #pragma unroll
    for (int i = 0; i < 4; i++)
        #pragma unroll
        for (int j = 0; j < 2; j++)
            acc[i][j] = f32x4{0.f, 0.f, 0.f, 0.f};

    // staging: 1024 chunks per matrix, 512 threads -> 2 each (shared mapping)
    int sr[2], sc[2];
    #pragma unroll
    for (int j = 0; j < 2; j++) {
        int q = j * 512 + tid;
        sr[j] = q >> 3;
        sc[j] = ((q & 7) ^ (sr[j] & 7)) << 3;   // pre-swizzled source col (elems)
    }

    // fragment read offsets (loop-invariant)
    int roA[4], coA[4], roB[2], coB[2];
    #pragma unroll
    for (int i = 0; i < 4; i++) {
        int r = wr * 64 + i * 16 + l16;
        roA[i] = r * 64; coA[i] = quad ^ (r & 7);
    }
    #pragma unroll
    for (int j = 0; j < 2; j++) {
        int r = wc * 32 + j * 16 + l16;
        roB[j] = r * 64; coB[j] = quad ^ (r & 7);
    }

    for (int k0 = 0; k0 < k_len; k0 += 64) {
        // B -> LDS async
        #pragma unroll
        for (int j = 0; j < 2; j++)
            async_copy16(&Bs[(j * 512 + tid) * 8], Bg + (size_t)sr[j] * ldb + k0 + sc[j]);
        // A: fp32 loads to regs
        float4 f0[2], f1[2];
        #pragma unroll
        for (int j = 0; j < 2; j++) {
            const float* p = Xg + (size_t)sr[j] * ldx + k0 + sc[j];
            f0[j] = ((const float4*)p)[0];
            f1[j] = ((const float4*)p)[1];
        }
        asm volatile("s_waitcnt vmcnt(0)" ::: "memory");
        // convert + linear ds_write (conflict-free)
        #pragma unroll
        for (int j = 0; j < 2; j++) {
            u16x8 o;
            o[0] = f2b(f0[j].x); o[1] = f2b(f0[j].y); o[2] = f2b(f0[j].z); o[3] = f2b(f0[j].w);
            o[4] = f2b(f1[j].x); o[5] = f2b(f1[j].y); o[6] = f2b(f1[j].z); o[7] = f2b(f1[j].w);
            *(u16x8*)&As[(size_t)(j * 512 + tid) * 8] = o;
        }
        __syncthreads();

        #pragma unroll
        for (int s = 0; s < 2; s++) {
            bf16x8 av[4], bv[2];
            #pragma unroll
            for (int i = 0; i < 4; i++)
                av[i] = *(const bf16x8*)&As[roA[i] + ((coA[i] ^ (s << 2)) << 3)];
            #pragma unroll
            for (int j = 0; j < 2; j++)
                bv[j] = *(const bf16x8*)&Bs[roB[j] + ((coB[j] ^ (s << 2)) << 3)];
            #pragma unroll
            for (int i = 0; i < 4; i++)
                #pragma unroll
                for (int j = 0; j < 2; j++)
                    acc[i][j] = __builtin_amdgcn_mfma_f32_16x16x32_bf16(av[i], bv[j], acc[i][j], 0, 0, 0);
        }
        __syncthreads();
    }

    #pragma unroll
    for (int i = 0; i < 4; i++) {
        int rbase = bm * 128 + wr * 64 + i * 16 + quad * 4;
        #pragma unroll
        for (int j = 0; j < 2; j++) {
            int col = bn * 128 + wc * 32 + j * 16 + l16;
            float bc = bias[col];
            #pragma unroll
            for (int r = 0; r < 4; r++)
                Out[(size_t)(rbase + r) * ldout + col] = f2b(fast_tanh(acc[i][j][r] + bc));
        }
    }
}

// ---------- GEMM2: 256x256 tile, BK=64, 4-phase counted-vmcnt (frozen r5) ----------

template <int LBN>
__global__ __launch_bounds__(512, 2)
void k_gemm256(const unsigned short* __restrict__ A,
               const unsigned short* __restrict__ B,
               const float* __restrict__ bias,
               unsigned short* __restrict__ Out, int ldout,
               int lda, int ldb, int k_len) {
    __shared__ __align__(16) unsigned short As[2][256 * 64];
    __shared__ __align__(16) unsigned short Bs[2][256 * 64];

    const int tid  = threadIdx.x;
    const int wave = tid >> 6;
    const int lane = tid & 63;
    const int quad = lane >> 4;
    const int l16  = lane & 15;
    const int wm   = wave >> 2;     // 0..1
    const int wn   = wave & 3;      // 0..3

    const int bid = blockIdx.x;
    const int xcd = bid & 7;
    const int lid = bid >> 3;
    const int bn  = lid & ((1 << LBN) - 1);
    const int bm  = (lid >> LBN) * 8 + xcd;

    const unsigned short* Ag = A + (size_t)(bm * 256) * lda;
    const unsigned short* Bg = B + (size_t)(bn * 256) * ldb;

    // staging per-thread constants (chunk q = u*512 + tid; lds row = u*64 + rr)
    const int rr = tid >> 3;
    const int sc = ((tid & 7) ^ (rr & 7)) << 3;
    int gA[4], gB[4];
    #pragma unroll
    for (int u = 0; u < 4; u++) {
        gA[u] = (u & 1) * 128 + (u >> 1) * 64 + rr;
        gB[u] = ((u & 1) * 2 + (rr >> 5)) * 64 + (u >> 1) * 32 + (rr & 31);
    }

    // fragment read offsets: lds rows per permuted layout; lr&7 == l16&7 always
    const int co = quad ^ (l16 & 7);
    int baseA[8], baseB[4];
    #pragma unroll
    for (int i = 0; i < 8; i++)
        baseA[i] = ((i >> 2) * 128 + wm * 64 + (i & 3) * 16 + l16) * 64;
    #pragma unroll
    for (int j = 0; j < 4; j++)
        baseB[j] = ((j >> 1) * 128 + wn * 32 + (j & 1) * 16 + l16) * 64;

    f32x4 acc[8][4];
    #pragma unroll
    for (int i = 0; i < 8; i++)
        #pragma unroll
        for (int j = 0; j < 4; j++)
            acc[i][j] = f32x4{0.f, 0.f, 0.f, 0.f};

    // four DISJOINT fragment sets
    bf16x8 avA[2][4], avB[2][4], bv0[2][2], bv1[2][2];

    auto stageA2 = [&](int buf, int u0, int k0) {
        #pragma unroll
        for (int d = 0; d < 2; d++) {
            int u = u0 + d;
            async_copy16(&As[buf][(u * 512 + wave * 64) * 8],
                         Ag + (size_t)gA[u] * lda + k0 + sc);
        }
    };
    auto stageB2 = [&](int buf, int u0, int k0) {
        #pragma unroll
        for (int d = 0; d < 2; d++) {
            int u = u0 + d;
            async_copy16(&Bs[buf][(u * 512 + wave * 64) * 8],
                         Bg + (size_t)gB[u] * ldb + k0 + sc);
        }
    };
    auto readA = [&](int buf, int mh, bf16x8 (&av)[2][4]) {
        #pragma unroll
        for (int s = 0; s < 2; s++)
            #pragma unroll
            for (int i = 0; i < 4; i++)
                av[s][i] = *(const bf16x8*)&As[buf][baseA[mh * 4 + i] + ((co ^ (s << 2)) << 3)];
    };
    auto readB = [&](int buf, int nh, bf16x8 (&bv)[2][2]) {
        #pragma unroll
        for (int s = 0; s < 2; s++)
            #pragma unroll
            for (int j = 0; j < 2; j++)
                bv[s][j] = *(const bf16x8*)&Bs[buf][baseB[nh * 2 + j] + ((co ^ (s << 2)) << 3)];
    };
    auto mmaQ = [&](int mh, int nh, bf16x8 (&av)[2][4], bf16x8 (&bv)[2][2]) {
        __builtin_amdgcn_s_setprio(1);
        #pragma unroll
        for (int s = 0; s < 2; s++)
            #pragma unroll
            for (int i = 0; i < 4; i++)
                #pragma unroll
                for (int j = 0; j < 2; j++)
                    acc[mh * 4 + i][nh * 2 + j] = __builtin_amdgcn_mfma_f32_16x16x32_bf16(
                        av[s][i], bv[s][j], acc[mh * 4 + i][nh * 2 + j], 0, 0, 0);
        __builtin_amdgcn_s_setprio(0);
    };

    auto tile = [&](int rb, int k0n) {
        const int sb = rb ^ 1;
        // p1: quadrant (mh0, nh0)
        readA(rb, 0, avA); readB(rb, 0, bv0);
        stageA2(sb, 0, k0n);
        asm volatile("s_waitcnt vmcnt(4)" ::: "memory");
        asm volatile("s_barrier" ::: "memory");
        mmaQ(0, 0, avA, bv0);
        asm volatile("s_barrier" ::: "memory");
        // p2: quadrant (mh1, nh0)
        readA(rb, 1, avB);
        stageB2(sb, 0, k0n);
        asm volatile("s_waitcnt vmcnt(4)" ::: "memory");
        asm volatile("s_barrier" ::: "memory");
        mmaQ(1, 0, avB, bv0);
        asm volatile("s_barrier" ::: "memory");
        // p3: quadrant (mh0, nh1)
        readB(rb, 1, bv1);
        stageA2(sb, 2, k0n);
        asm volatile("s_waitcnt vmcnt(4)" ::: "memory");
        asm volatile("s_barrier" ::: "memory");
        mmaQ(0, 1, avA, bv1);
        asm volatile("s_barrier" ::: "memory");
        // p4: quadrant (mh1, nh1) — no reads
        stageB2(sb, 2, k0n);
        asm volatile("s_waitcnt vmcnt(4)" ::: "memory");
        asm volatile("s_barrier" ::: "memory");
        mmaQ(1, 1, avB, bv1);
        asm volatile("s_barrier" ::: "memory");
    };

    // prologue: stage tile 0 in steady-state order A0,B0,A1,B1
    stageA2(0, 0, 0);
    stageB2(0, 0, 0);
    stageA2(0, 2, 0);
    stageB2(0, 2, 0);
    asm volatile("s_waitcnt vmcnt(4)" ::: "memory");
    asm volatile("s_barrier" ::: "memory");

    const int NT = k_len >> 6;   // must be even
    for (int kt = 0; kt < NT; kt += 2) {
        int k1 = (kt + 1) * 64;
        int k2 = (kt + 2 < NT ? kt + 2 : 0) * 64;   // wrap: tail loads harmless
        tile(0, k1);
        tile(1, k2);
    }

    #pragma unroll
    for (int i = 0; i < 8; i++) {
        int rbase = bm * 256 + wm * 128 + i * 16 + quad * 4;
        #pragma unroll
        for (int j = 0; j < 4; j++) {
            int col = bn * 256 + wn * 64 + j * 16 + l16;
            float bc = bias[col];
            #pragma unroll
            for (int r = 0; r < 4; r++)
                Out[(size_t)(rbase + r) * ldout + col] = f2b(acc[i][j][r] + bc);
        }
    }
}

// ---------- tau: per-row sparsemax threshold (bisection), one WAVE per row ----------
__global__ __launch_bounds__(256)
void k_tau(const unsigned short* __restrict__ a, float* __restrict__ tau_out) {
    const int wave = threadIdx.x >> 6;
    const int lane = threadIdx.x & 63;
    const int row = blockIdx.x * 4 + wave;

    const u16x8* ar = (const u16x8*)(a + (size_t)row * 4096);
    float v[64];
    #pragma unroll
    for (int j = 0; j < 8; j++) {
        u16x8 u = ar[lane + 64 * j];
        #pragma unroll
        for (int k = 0; k < 8; k++) v[j * 8 + k] = b2f(u[k]);
    }

    float m = v[0];
    #pragma unroll
    for (int i = 1; i < 64; i++) m = fmaxf(m, v[i]);
    #pragma unroll
    for (int off = 1; off < 64; off <<= 1) m = fmaxf(m, __shfl_xor(m, off));

    float lo = m - 1.0f, hi = m;
    #pragma unroll 1
    for (int it = 0; it < 14; ++it) {
        float mid = 0.5f * (lo + hi);
        float s = 0.f;
        #pragma unroll
        for (int i = 0; i < 64; i++) s += fmaxf(v[i] - mid, 0.f);
        #pragma unroll
        for (int off = 1; off < 64; off <<= 1) s += __shfl_xor(s, off);
        if (s > 1.0f) lo = mid; else hi = mid;
    }
    if (lane == 0) tau_out[row] = 0.5f * (lo + hi);
}

// ---------- GEMM3 w/ fused gating: P3[kz] = (x*max(a-tau,0)) @ Wc1 ----------
// 256 threads, 128x128 tile, BK=64, split-K=4 (grid: x=1, y=bm, z=kz).
// A operand computed on the fly: read abf (bf16) + x (fp32 direct), gate in
// fp32, f2b, LINEAR ds_write_b128 (source pre-swizzled -> conflict-free).
// B staged via global_load_lds.

__global__ __launch_bounds__(256, 3)
void k_gemm3g(const unsigned short* __restrict__ A,   // abf [8192][4096] bf16
              const float* __restrict__ X,            // x   [8192][4096] fp32
              const float* __restrict__ tau,
              const unsigned short* __restrict__ B,   // Wc1t [128][4096] bf16
              float* __restrict__ Out, int ldout,
              int lda, int ldx, int ldb, int k_len, size_t pstride) {
    __shared__ __align__(16) unsigned short As[128 * 64];
    __shared__ __align__(16) unsigned short Bs[128 * 64];

    const int tid  = threadIdx.x;
    const int wave = tid >> 6;
    const int lane = tid & 63;
    const int quad = lane >> 4;
    const int l16  = lane & 15;
    const int wr   = wave >> 1;
    const int wc   = wave & 1;

    const int bm = blockIdx.y;
    const int kz = blockIdx.z;

    const unsigned short* Ag = A + (size_t)(bm * 128) * lda + (size_t)kz * k_len;
    const float*          Xg = X + (size_t)(bm * 128) * ldx + (size_t)kz * k_len;
    const unsigned short* Bg = B + (size_t)kz * k_len;

    f32x4 acc[4][4];
    #pragma unroll
    for (int i = 0; i < 4; i++)
        #pragma unroll
        for (int j = 0; j < 4; j++)
            acc[i][j] = f32x4{0.f, 0.f, 0.f, 0.f};

    // A/X reg-staging: chunk q = j*256+tid; source col pre-swizzled; dst linear
    int ar[4], acm[4];
    float taur[4];
    #pragma unroll
    for (int j = 0; j < 4; j++) {
        int q = j * 256 + tid;
        ar[j]  = q >> 3;
        acm[j] = ((q & 7) ^ (ar[j] & 7)) << 3;
        taur[j] = tau[bm * 128 + ar[j]];
    }

    // B staging via global_load_lds: pre-swizzled source (same mapping)
    int sr[4], sc[4];
    #pragma unroll
    for (int j = 0; j < 4; j++) {
        int q = j * 256 + tid;
        sr[j] = q >> 3;
        sc[j] = ((q & 7) ^ (sr[j] & 7)) << 3;
    }

    int roA[4], coA[4], roB[4], coB[4];
    #pragma unroll
    for (int i = 0; i < 4; i++) {
        int ra = wr * 64 + i * 16 + l16;
        roA[i] = ra * 64; coA[i] = quad ^ (ra & 7);
        int rb = wc * 64 + i * 16 + l16;
        roB[i] = rb * 64; coB[i] = quad ^ (rb & 7);
    }

    for (int k0 = 0; k0 < k_len; k0 += 64) {
        #pragma unroll
        for (int j = 0; j < 4; j++)
            async_copy16(&Bs[(j * 256 + tid) * 8], Bg + (size_t)sr[j] * ldb + k0 + sc[j]);
        #pragma unroll
        for (int j = 0; j < 4; j++) {
            u16x8 av = *(const u16x8*)(Ag + (size_t)ar[j] * lda + k0 + acm[j]);
            const float* xp = Xg + (size_t)ar[j] * ldx + k0 + acm[j];
            float4 x0 = ((const float4*)xp)[0];
            float4 x1 = ((const float4*)xp)[1];
            float xe[8] = {x0.x, x0.y, x0.z, x0.w, x1.x, x1.y, x1.z, x1.w};
            u16x8 o;
            #pragma unroll
            for (int e = 0; e < 8; e++)
                o[e] = f2b(fmaxf(b2f(av[e]) - taur[j], 0.f) * xe[e]);
            *(u16x8*)&As[(size_t)(j * 256 + tid) * 8] = o;
        }
        asm volatile("s_waitcnt vmcnt(0)" ::: "memory");
        __syncthreads();

        #pragma unroll
        for (int s = 0; s < 2; s++) {
            bf16x8 av[4], bv[4];
            #pragma unroll
            for (int i = 0; i < 4; i++)
                av[i] = *(const bf16x8*)&As[roA[i] + ((coA[i] ^ (s << 2)) << 3)];
            #pragma unroll
            for (int j = 0; j < 4; j++)
                bv[j] = *(const bf16x8*)&Bs[roB[j] + ((coB[j] ^ (s << 2)) << 3)];
            #pragma unroll
            for (int i = 0; i < 4; i++)
                #pragma unroll
                for (int j = 0; j < 4; j++)
                    acc[i][j] = __builtin_amdgcn_mfma_f32_16x16x32_bf16(av[i], bv[j], acc[i][j], 0, 0, 0);
        }
        __syncthreads();
    }

    #pragma unroll
    for (int i = 0; i < 4; i++) {
        int rbase = bm * 128 + wr * 64 + i * 16 + quad * 4;
        #pragma unroll
        for (int j = 0; j < 4; j++) {
            int col = wc * 64 + j * 16 + l16;
            #pragma unroll
            for (int r = 0; r < 4; r++)
                Out[kz * pstride + (size_t)(rbase + r) * ldout + col] = acc[i][j][r];
        }
    }
}

// ---------- final: out = relu(sum_p P[p] + bc1) @ Wc2 + bc2 ----------
__global__ __launch_bounds__(256)
void k_final(const float* __restrict__ P, const float* __restrict__ bc1,
             const float* __restrict__ Wc2, const float* __restrict__ bc2,
             float* __restrict__ out) {
    __shared__ float w2s[128 * 16];
    __shared__ float hs[4 * 128];
    const int tid = threadIdx.x;
    for (int i = tid; i < 2048; i += 256) w2s[i] = Wc2[i];

    #pragma unroll
    for (int i = tid; i < 512; i += 256) {
        int r = i >> 7, c = i & 127;
        int row = blockIdx.x * 4 + r;
        float s = bc1[c];
        #pragma unroll
        for (int p = 0; p < 4; p++)
            s += P[((size_t)p * 8192 + row) * 128 + c];
        hs[i] = fmaxf(s, 0.f);
    }
    __syncthreads();

    const int wave = tid >> 6, lane = tid & 63;
    const int row = blockIdx.x * 4 + wave;
    const int c = lane & 15, hq = lane >> 4;
    float acc = 0.f;
    #pragma unroll
    for (int t = 0; t < 32; ++t) {
        int hidx = hq * 32 + t;
        acc += hs[wave * 128 + hidx] * w2s[hidx * 16 + c];
    }
    acc += __shfl_xor(acc, 16);
    acc += __shfl_xor(acc, 32);
    if (hq == 0) out[(size_t)row * 16 + c] = acc + bc2[c];
}

// ---------- launch ----------

extern "C" void kernel_launch(void* const* d_in, const int* in_sizes, int n_in,
                              void* d_out, int out_size, void* d_ws, size_t ws_size,
                              hipStream_t stream) {
    (void)in_sizes; (void)n_in; (void)out_size; (void)ws_size;
    const float* x   = (const float*)d_in[0];
    const float* W1  = (const float*)d_in[1];
    const float* b1  = (const float*)d_in[2];
    const float* W2  = (const float*)d_in[3];
    const float* b2  = (const float*)d_in[4];
    const float* Wc1 = (const float*)d_in[5];
    const float* bc1 = (const float*)d_in[6];
    const float* Wc2 = (const float*)d_in[7];
    const float* bc2 = (const float*)d_in[8];
    float* out = (float*)d_out;

    char* ws = (char*)d_ws;
    float*          P3   = (float*)         (ws);                  // 0..16 MB   GEMM3 partials (split-K=4)
    unsigned short* W1t  = (unsigned short*)(ws + (64ll  << 20));  // 64..72     dead after GEMM1
    unsigned short* Tb   = (unsigned short*)(ws + (72ll  << 20));  // 72..88     dead after GEMM2
    unsigned short* W2t  = (unsigned short*)(ws + (88ll  << 20));  // 88..96     dead after GEMM2
    unsigned short* abf  = (unsigned short*)(ws + (96ll  << 20));  // 96..160    a bf16 (alive thru GEMM3)
    unsigned short* Wc1t = (unsigned short*)(ws + (160ll << 20));  // 160..161
    float*          tauv = (float*)         (ws + (168ll << 20));  // 168..168.03

    dim3 tb(32, 8);
    k_transpose_cvt<<<dim3(1024 / 32, 4096 / 32), tb, 0, stream>>>(W1, W1t, 4096, 1024);
    k_transpose_cvt<<<dim3(4096 / 32, 1024 / 32), tb, 0, stream>>>(W2, W2t, 1024, 4096);
    k_transpose_cvt<<<dim3(128 / 32, 4096 / 32), tb, 0, stream>>>(Wc1, Wc1t, 4096, 128);

    // T = tanh(x @ W1 + b1)  [8192][1024] bf16 — x read fp32 directly (no cvt pass)
    k_gemm_tanh<<<512, 512, 0, stream>>>(x, W1t, b1, Tb, 1024, 4096, 4096, 4096);
    // a = T @ W2 + b2  [8192][4096] bf16 — 256² 4-phase (32 bm x 16 bn, LBN=4)
    k_gemm256<4><<<512, 512, 0, stream>>>(Tb, W2t, b2, abf, 4096, 1024, 1024, 1024);
    // tau per row (sparsemax threshold only)
    k_tau<<<2048, 256, 0, stream>>>(abf, tauv);
    // GEMM3 split-K=4 with fused gating: P3[kz] = (x*max(a-tau,0)) @ Wc1
    k_gemm3g<<<dim3(1, 64, 4), 256, 0, stream>>>(abf, x, tauv, Wc1t, P3, 128,
                                                 4096, 4096, 4096, 1024, (size_t)8192 * 128);
    // out = relu(sum P3 + bc1) @ Wc2 + bc2
    k_final<<<2048, 256, 0, stream>>>(P3, bc1, Wc2, bc2, out);
}

// Round 7
// 433.616 us; speedup vs baseline: 1.1614x; 1.1614x over previous
//
#include <hip/hip_runtime.h>
#include <cstdint>

// ---------- common helpers ----------

typedef __bf16 bf16x8 __attribute__((ext_vector_type(8)));
typedef float  f32x4  __attribute__((ext_vector_type(4)));
typedef unsigned short u16x8 __attribute__((ext_vector_type(8)));

__device__ __forceinline__ unsigned short f2b(float f) {
    union { float f; unsigned u; } v; v.f = f;
    unsigned r = v.u + 0x7FFFu + ((v.u >> 16) & 1u);   // RNE
    return (unsigned short)(r >> 16);
}

__device__ __forceinline__ float b2f(unsigned short u) {
    union { unsigned u; float f; } v; v.u = ((unsigned)u) << 16;
    return v.f;
}

__device__ __forceinline__ float fast_tanh(float x) {
    // tanh(x) = 1 - 2/(e^{2x}+1); e^{2x} = 2^(x*2*log2 e). err ~1e-6 << bf16 eps
    float e = __builtin_amdgcn_exp2f(2.885390082f * x);
    return 1.0f - 2.0f * __builtin_amdgcn_rcpf(e + 1.0f);
}

__device__ __forceinline__ void async_copy16(void* lds, const void* g) {
    __builtin_amdgcn_global_load_lds(
        (const __attribute__((address_space(1))) unsigned int*)g,
        (__attribute__((address_space(3))) unsigned int*)lds,
        16, 0, 0);
}

// LDS layout (BK=64): tiles stored as 16B chunks; slot q (linear) holds global
// chunk (r=q>>3, c=(q&7)^(r&7)).
// => global chunk (r,c) lives at elem offset r*64 + ((c^(r&7))<<3).
// ds_read banks: addr/4 = 32r + 4(c^(r&7)) -> 2-way max (free, m136).

// ---------- merged prep: x->bf16 cvt + 3 weight transposes, ONE dispatch ----------
// blocks [0,32768): cvt x (float4->ushort4)
// blocks [32768,36864): W1 [4096][1024] -> W1t
// blocks [36864,40960): W2 [1024][4096] -> W2t
// blocks [40960,41472): Wc1 [4096][128] -> Wc1t

__global__ __launch_bounds__(256)
void k_prep(const float* __restrict__ x, unsigned short* __restrict__ xb,
            const float* __restrict__ W1, unsigned short* __restrict__ W1t,
            const float* __restrict__ W2, unsigned short* __restrict__ W2t,
            const float* __restrict__ Wc1, unsigned short* __restrict__ Wc1t) {
    const int b = blockIdx.x;
    if (b < 32768) {
        int i = b * 256 + threadIdx.x;
        float4 f = ((const float4*)x)[i];
        ((ushort4*)xb)[i] = make_ushort4(f2b(f.x), f2b(f.y), f2b(f.z), f2b(f.w));
        return;
    }
    const float* in; unsigned short* out; int R, C, rb;
    if (b < 36864)      { in = W1;  out = W1t;  R = 4096; C = 1024; rb = b - 32768; }
    else if (b < 40960) { in = W2;  out = W2t;  R = 1024; C = 4096; rb = b - 36864; }
    else                { in = Wc1; out = Wc1t; R = 4096; C = 128;  rb = b - 40960; }
    const int nbx = C >> 5;
    const int bc = (rb % nbx) * 32, br = (rb / nbx) * 32;
    const int tx = threadIdx.x & 31, ty = threadIdx.x >> 5;   // (32, 8)
    __shared__ float tile[32][33];
    #pragma unroll
    for (int i = 0; i < 32; i += 8)
        tile[ty + i][tx] = in[(size_t)(br + ty + i) * C + bc + tx];
    __syncthreads();
    #pragma unroll
    for (int i = 0; i < 32; i += 8)
        out[(size_t)(bc + ty + i) * R + br + tx] = f2b(tile[tx][ty + i]);
}

// ---------- GEMM1: 512-thread 128x128 tile, BK=64, bias+tanh -> bf16 ----------
// XCD-swizzled 1-D grid: bm % 8 == xcd. 8 waves, wave tile 64x32.
// Best-measured structure for this shape (r1: ~76us, MfmaUtil ~36%).

__global__ __launch_bounds__(512, 4)
void k_gemm_tanh(const unsigned short* __restrict__ A,
                 const unsigned short* __restrict__ B,
                 const float* __restrict__ bias,
                 unsigned short* __restrict__ Out, int ldout,
                 int lda, int ldb, int k_len) {
    __shared__ __align__(16) unsigned short As[128 * 64];
    __shared__ __align__(16) unsigned short Bs[128 * 64];

    const int tid  = threadIdx.x;
    const int wave = tid >> 6;      // 0..7
    const int lane = tid & 63;
    const int quad = lane >> 4;
    const int l16  = lane & 15;
    const int wr   = wave >> 2;     // 0..1 : 64-row half
    const int wc   = wave & 3;      // 0..3 : 32-col quarter

    const int bid = blockIdx.x;
    const int xcd = bid & 7;
    const int lid = bid >> 3;
    const int bn  = lid & 7;
    const int bm  = (lid >> 3) * 8 + xcd;

    const unsigned short* Ag = A + (size_t)(bm * 128) * lda;
    const unsigned short* Bg = B + (size_t)(bn * 128) * ldb;

    f32x4 acc[4][2];
    #pragma unroll
    for (int i = 0; i < 4; i++)
        #pragma unroll
        for (int j = 0; j < 2; j++)
            acc[i][j] = f32x4{0.f, 0.f, 0.f, 0.f};

    // staging: 1024 chunks per matrix, 512 threads -> 2 issues each
    int sr[2], sc[2];
    #pragma unroll
    for (int j = 0; j < 2; j++) {
        int q = j * 512 + wave * 64 + lane;
        sr[j] = q >> 3;
        sc[j] = ((q & 7) ^ (sr[j] & 7)) << 3;   // element offset of source chunk
    }

    // fragment read offsets (loop-invariant)
    int roA[4], coA[4], roB[2], coB[2];
    #pragma unroll
    for (int i = 0; i < 4; i++) {
        int r = wr * 64 + i * 16 + l16;
        roA[i] = r * 64; coA[i] = quad ^ (r & 7);
    }
    #pragma unroll
    for (int j = 0; j < 2; j++) {
        int r = wc * 32 + j * 16 + l16;
        roB[j] = r * 64; coB[j] = quad ^ (r & 7);
    }

    for (int k0 = 0; k0 < k_len; k0 += 64) {
        #pragma unroll
        for (int j = 0; j < 2; j++) {
            async_copy16(&As[(j * 512 + wave * 64) * 8], Ag + (size_t)sr[j] * lda + k0 + sc[j]);
            async_copy16(&Bs[(j * 512 + wave * 64) * 8], Bg + (size_t)sr[j] * ldb + k0 + sc[j]);
        }
        asm volatile("s_waitcnt vmcnt(0)" ::: "memory");
        __syncthreads();

        #pragma unroll
        for (int s = 0; s < 2; s++) {
            bf16x8 av[4], bv[2];
            #pragma unroll
            for (int i = 0; i < 4; i++)
                av[i] = *(const bf16x8*)&As[roA[i] + ((coA[i] ^ (s << 2)) << 3)];
            #pragma unroll
            for (int j = 0; j < 2; j++)
                bv[j] = *(const bf16x8*)&Bs[roB[j] + ((coB[j] ^ (s << 2)) << 3)];
            #pragma unroll
            for (int i = 0; i < 4; i++)
                #pragma unroll
                for (int j = 0; j < 2; j++)
                    acc[i][j] = __builtin_amdgcn_mfma_f32_16x16x32_bf16(av[i], bv[j], acc[i][j], 0, 0, 0);
        }
        __syncthreads();
    }

    #pragma unroll
    for (int i = 0; i < 4; i++) {
        int rbase = bm * 128 + wr * 64 + i * 16 + quad * 4;
        #pragma unroll
        for (int j = 0; j < 2; j++) {
            int col = bn * 128 + wc * 32 + j * 16 + l16;
            float bc = bias[col];
            #pragma unroll
            for (int r = 0; r < 4; r++)
                Out[(size_t)(rbase + r) * ldout + col] = f2b(fast_tanh(acc[i][j][r] + bc));
        }
    }
}

// ---------- GEMM2: 256x256 tile, BK=64, 8-phase counted-vmcnt (r1 frozen) ----------

template <int LBN>
__global__ __launch_bounds__(512, 2)
void k_gemm256(const unsigned short* __restrict__ A,
               const unsigned short* __restrict__ B,
               const float* __restrict__ bias,
               unsigned short* __restrict__ Out, int ldout,
               int lda, int ldb, int k_len) {
    __shared__ __align__(16) unsigned short As[2][256 * 64];
    __shared__ __align__(16) unsigned short Bs[2][256 * 64];

    const int tid  = threadIdx.x;
    const int wave = tid >> 6;
    const int lane = tid & 63;
    const int quad = lane >> 4;
    const int l16  = lane & 15;
    const int wm   = wave >> 2;     // 0..1
    const int wn   = wave & 3;      // 0..3

    const int bid = blockIdx.x;
    const int xcd = bid & 7;
    const int lid = bid >> 3;
    const int bn  = lid & ((1 << LBN) - 1);
    const int bm  = (lid >> LBN) * 8 + xcd;

    const unsigned short* Ag = A + (size_t)(bm * 256) * lda;
    const unsigned short* Bg = B + (size_t)(bn * 256) * ldb;

    // staging per-thread constants (chunk q = u*512 + tid; lds row = u*64 + rr)
    const int rr = tid >> 3;
    const int sc = ((tid & 7) ^ (rr & 7)) << 3;
    int gA[4], gB[4];
    #pragma unroll
    for (int u = 0; u < 4; u++) {
        gA[u] = (u & 1) * 128 + (u >> 1) * 64 + rr;
        gB[u] = ((u & 1) * 2 + (rr >> 5)) * 64 + (u >> 1) * 32 + (rr & 31);
    }

    // fragment read offsets: lds rows per permuted layout; lr&7 == l16&7 always
    const int co = quad ^ (l16 & 7);
    int baseA[8], baseB[4];
    #pragma unroll
    for (int i = 0; i < 8; i++)
        baseA[i] = ((i >> 2) * 128 + wm * 64 + (i & 3) * 16 + l16) * 64;
    #pragma unroll
    for (int j = 0; j < 4; j++)
        baseB[j] = ((j >> 1) * 128 + wn * 32 + (j & 1) * 16 + l16) * 64;

    f32x4 acc[8][4];
    #pragma unroll
    for (int i = 0; i < 8; i++)
        #pragma unroll
        for (int j = 0; j < 4; j++)
            acc[i][j] = f32x4{0.f, 0.f, 0.f, 0.f};

    bf16x8 avq[2][4], bvA[2][2], bvB[2][2];

    auto stageA2 = [&](int buf, int u0, int k0) {
        #pragma unroll
        for (int d = 0; d < 2; d++) {
            int u = u0 + d;
            async_copy16(&As[buf][(u * 512 + wave * 64) * 8],
                         Ag + (size_t)gA[u] * lda + k0 + sc);
        }
    };
    auto stageB2 = [&](int buf, int u0, int k0) {
        #pragma unroll
        for (int d = 0; d < 2; d++) {
            int u = u0 + d;
            async_copy16(&Bs[buf][(u * 512 + wave * 64) * 8],
                         Bg + (size_t)gB[u] * ldb + k0 + sc);
        }
    };
    auto readA = [&](int buf, int mh) {
        #pragma unroll
        for (int s = 0; s < 2; s++)
            #pragma unroll
            for (int i = 0; i < 4; i++)
                avq[s][i] = *(const bf16x8*)&As[buf][baseA[mh * 4 + i] + ((co ^ (s << 2)) << 3)];
    };
    auto readB = [&](int buf, int nh, bf16x8 (&bv)[2][2]) {
        #pragma unroll
        for (int s = 0; s < 2; s++)
            #pragma unroll
            for (int j = 0; j < 2; j++)
                bv[s][j] = *(const bf16x8*)&Bs[buf][baseB[nh * 2 + j] + ((co ^ (s << 2)) << 3)];
    };
    auto mmaQ = [&](int mh, int nh, bf16x8 (&bv)[2][2]) {
        __builtin_amdgcn_s_setprio(1);
        #pragma unroll
        for (int s = 0; s < 2; s++)
            #pragma unroll
            for (int i = 0; i < 4; i++)
                #pragma unroll
                for (int j = 0; j < 2; j++)
                    acc[mh * 4 + i][nh * 2 + j] = __builtin_amdgcn_mfma_f32_16x16x32_bf16(
                        avq[s][i], bv[s][j], acc[mh * 4 + i][nh * 2 + j], 0, 0, 0);
        __builtin_amdgcn_s_setprio(0);
    };

    auto tile = [&](int rb, int k0n) {
        const int sb = rb ^ 1;
        // phase 1: quadrant (mh0, nh0)
        readA(rb, 0); readB(rb, 0, bvA);
        stageA2(sb, 0, k0n);
        asm volatile("s_waitcnt vmcnt(4)" ::: "memory");
        asm volatile("s_barrier" ::: "memory");
        mmaQ(0, 0, bvA);
        asm volatile("s_barrier" ::: "memory");
        // phase 2: quadrant (mh0, nh1)
        readB(rb, 1, bvB);
        stageB2(sb, 0, k0n);
        asm volatile("s_waitcnt vmcnt(4)" ::: "memory");
        asm volatile("s_barrier" ::: "memory");
        mmaQ(0, 1, bvB);
        asm volatile("s_barrier" ::: "memory");
        // phase 3: quadrant (mh1, nh1)
        readA(rb, 1);
        stageB2(sb, 2, k0n);
        asm volatile("s_waitcnt vmcnt(4)" ::: "memory");
        asm volatile("s_barrier" ::: "memory");
        mmaQ(1, 1, bvB);
        asm volatile("s_barrier" ::: "memory");
        // phase 4: quadrant (mh1, nh0) — bvA still live from phase 1
        stageA2(sb, 2, k0n);
        asm volatile("s_waitcnt vmcnt(4)" ::: "memory");
        asm volatile("s_barrier" ::: "memory");
        mmaQ(1, 0, bvA);
        asm volatile("s_barrier" ::: "memory");
    };

    // prologue: stage tile 0 in steady-state order A01, B01, B23, A23
    stageA2(0, 0, 0);
    stageB2(0, 0, 0);
    stageB2(0, 2, 0);
    stageA2(0, 2, 0);
    asm volatile("s_waitcnt vmcnt(4)" ::: "memory");
    asm volatile("s_barrier" ::: "memory");

    const int NT = k_len >> 6;   // must be even
    for (int kt = 0; kt < NT; kt += 2) {
        int k1 = (kt + 1) * 64;
        int k2 = (kt + 2 < NT ? kt + 2 : 0) * 64;   // wrap: tail loads harmless
        tile(0, k1);
        tile(1, k2);
    }

    #pragma unroll
    for (int i = 0; i < 8; i++) {
        int rbase = bm * 256 + wm * 128 + i * 16 + quad * 4;
        #pragma unroll
        for (int j = 0; j < 4; j++) {
            int col = bn * 256 + wn * 64 + j * 16 + l16;
            float bc = bias[col];
            #pragma unroll
            for (int r = 0; r < 4; r++)
                Out[(size_t)(rbase + r) * ldout + col] = f2b(acc[i][j][r] + bc);
        }
    }
}

// ---------- 256-thread 128x128 GEMM, BK=64 ----------
// MODE 2: store fp32 partial at Out + kz*pstride (split-K, 3-D grid)

template <int MODE, int LBN>
__global__ __launch_bounds__(256, 3)
void k_gemm(const unsigned short* __restrict__ A,
            const unsigned short* __restrict__ B,
            const float* __restrict__ bias,
            void* __restrict__ Out, int ldout,
            int lda, int ldb, int k_len, size_t pstride) {
    __shared__ __align__(16) unsigned short As[128 * 64];
    __shared__ __align__(16) unsigned short Bs[128 * 64];

    const int tid  = threadIdx.x;
    const int wave = tid >> 6;
    const int lane = tid & 63;
    const int quad = lane >> 4;
    const int l16  = lane & 15;
    const int wr   = wave >> 1;
    const int wc   = wave & 1;

    int bn, bm, kz;
    if (LBN >= 0) {
        const int bid = blockIdx.x;
        const int xcd = bid & 7;
        const int lid = bid >> 3;
        bn = lid & ((1 << LBN) - 1);
        bm = (lid >> LBN) * 8 + xcd;    // bm % 8 == xcd
        kz = 0;
    } else {
        bn = blockIdx.x; bm = blockIdx.y; kz = blockIdx.z;
    }

    const unsigned short* Ag = A + (size_t)(bm * 128) * lda + (size_t)kz * k_len;
    const unsigned short* Bg = B + (size_t)(bn * 128) * ldb + (size_t)kz * k_len;

    f32x4 acc[4][4];
    #pragma unroll
    for (int i = 0; i < 4; i++)
        #pragma unroll
        for (int j = 0; j < 4; j++)
            acc[i][j] = f32x4{0.f, 0.f, 0.f, 0.f};

    // staging: 1024 chunks per matrix, 256 threads -> 4 issues each
    int sr[4], sc[4];
    #pragma unroll
    for (int j = 0; j < 4; j++) {
        int q = j * 256 + wave * 64 + lane;
        sr[j] = q >> 3;
        sc[j] = ((q & 7) ^ (sr[j] & 7)) << 3;
    }

    int roA[4], coA[4], roB[4], coB[4];
    #pragma unroll
    for (int i = 0; i < 4; i++) {
        int ra = wr * 64 + i * 16 + l16;
        roA[i] = ra * 64; coA[i] = quad ^ (ra & 7);
        int rb = wc * 64 + i * 16 + l16;
        roB[i] = rb * 64; coB[i] = quad ^ (rb & 7);
    }

    for (int k0 = 0; k0 < k_len; k0 += 64) {
        #pragma unroll
        for (int j = 0; j < 4; j++) {
            async_copy16(&As[(j * 256 + wave * 64) * 8], Ag + (size_t)sr[j] * lda + k0 + sc[j]);
            async_copy16(&Bs[(j * 256 + wave * 64) * 8], Bg + (size_t)sr[j] * ldb + k0 + sc[j]);
        }
        asm volatile("s_waitcnt vmcnt(0)" ::: "memory");
        __syncthreads();

        #pragma unroll
        for (int s = 0; s < 2; s++) {
            bf16x8 av[4], bv[4];
            #pragma unroll
            for (int i = 0; i < 4; i++)
                av[i] = *(const bf16x8*)&As[roA[i] + ((coA[i] ^ (s << 2)) << 3)];
            #pragma unroll
            for (int j = 0; j < 4; j++)
                bv[j] = *(const bf16x8*)&Bs[roB[j] + ((coB[j] ^ (s << 2)) << 3)];
            #pragma unroll
            for (int i = 0; i < 4; i++)
                #pragma unroll
                for (int j = 0; j < 4; j++)
                    acc[i][j] = __builtin_amdgcn_mfma_f32_16x16x32_bf16(av[i], bv[j], acc[i][j], 0, 0, 0);
        }
        __syncthreads();
    }

    #pragma unroll
    for (int i = 0; i < 4; i++) {
        int rbase = bm * 128 + wr * 64 + i * 16 + quad * 4;
        #pragma unroll
        for (int j = 0; j < 4; j++) {
            int col = bn * 128 + wc * 64 + j * 16 + l16;
            #pragma unroll
            for (int r = 0; r < 4; r++) {
                int row = rbase + r;
                float val = acc[i][j][r];
                if (MODE == 1) {
                    val += bias[col];
                    ((unsigned short*)Out)[(size_t)row * ldout + col] = f2b(val);
                } else {
                    ((float*)Out)[kz * pstride + (size_t)row * ldout + col] = val;
                }
            }
        }
    }
}

// ---------- sparsemax + gating: one WAVE per row, zero barriers ----------
__global__ __launch_bounds__(256)
void k_sparsemax(const unsigned short* __restrict__ a,
                 const unsigned short* __restrict__ xb,
                 unsigned short* __restrict__ wout) {
    const int wave = threadIdx.x >> 6;
    const int lane = threadIdx.x & 63;
    const int row = blockIdx.x * 4 + wave;

    const u16x8* ar = (const u16x8*)(a + (size_t)row * 4096);
    float v[64];
    #pragma unroll
    for (int j = 0; j < 8; j++) {
        u16x8 u = ar[lane + 64 * j];
        #pragma unroll
        for (int k = 0; k < 8; k++) v[j * 8 + k] = b2f(u[k]);
    }

    float m = v[0];
    #pragma unroll
    for (int i = 1; i < 64; i++) m = fmaxf(m, v[i]);
    #pragma unroll
    for (int off = 1; off < 64; off <<= 1) m = fmaxf(m, __shfl_xor(m, off));

    float lo = m - 1.0f, hi = m;
    #pragma unroll 1
    for (int it = 0; it < 14; ++it) {
        float mid = 0.5f * (lo + hi);
        float s = 0.f;
        #pragma unroll
        for (int i = 0; i < 64; i++) s += fmaxf(v[i] - mid, 0.f);
        #pragma unroll
        for (int off = 1; off < 64; off <<= 1) s += __shfl_xor(s, off);
        if (s > 1.0f) lo = mid; else hi = mid;
    }
    float tau = 0.5f * (lo + hi);

    const u16x8* xr = (const u16x8*)(xb + (size_t)row * 4096);
    u16x8* wr_ = (u16x8*)(wout + (size_t)row * 4096);
    #pragma unroll
    for (int j = 0; j < 8; j++) {
        u16x8 xv = xr[lane + 64 * j];
        u16x8 o;
        #pragma unroll
        for (int k = 0; k < 8; k++)
            o[k] = f2b(fmaxf(v[j * 8 + k] - tau, 0.f) * b2f(xv[k]));
        wr_[lane + 64 * j] = o;
    }
}

// ---------- final: out = relu(sum_p P[p] + bc1) @ Wc2 + bc2 ----------
__global__ __launch_bounds__(256)
void k_final(const float* __restrict__ P, const float* __restrict__ bc1,
             const float* __restrict__ Wc2, const float* __restrict__ bc2,
             float* __restrict__ out) {
    __shared__ float w2s[128 * 16];
    __shared__ float hs[4 * 128];
    const int tid = threadIdx.x;
    for (int i = tid; i < 2048; i += 256) w2s[i] = Wc2[i];

    #pragma unroll
    for (int i = tid; i < 512; i += 256) {
        int r = i >> 7, c = i & 127;
        int row = blockIdx.x * 4 + r;
        float s = bc1[c];
        #pragma unroll
        for (int p = 0; p < 8; p++)
            s += P[((size_t)p * 8192 + row) * 128 + c];
        hs[i] = fmaxf(s, 0.f);
    }
    __syncthreads();

    const int wave = tid >> 6, lane = tid & 63;
    const int row = blockIdx.x * 4 + wave;
    const int c = lane & 15, hq = lane >> 4;
    float acc = 0.f;
    #pragma unroll
    for (int t = 0; t < 32; ++t) {
        int hidx = hq * 32 + t;
        acc += hs[wave * 128 + hidx] * w2s[hidx * 16 + c];
    }
    acc += __shfl_xor(acc, 16);
    acc += __shfl_xor(acc, 32);
    if (hq == 0) out[(size_t)row * 16 + c] = acc + bc2[c];
}

// ---------- launch ----------

extern "C" void kernel_launch(void* const* d_in, const int* in_sizes, int n_in,
                              void* d_out, int out_size, void* d_ws, size_t ws_size,
                              hipStream_t stream) {
    (void)in_sizes; (void)n_in; (void)out_size; (void)ws_size;
    const float* x   = (const float*)d_in[0];
    const float* W1  = (const float*)d_in[1];
    const float* b1  = (const float*)d_in[2];
    const float* W2  = (const float*)d_in[3];
    const float* b2  = (const float*)d_in[4];
    const float* Wc1 = (const float*)d_in[5];
    const float* bc1 = (const float*)d_in[6];
    const float* Wc2 = (const float*)d_in[7];
    const float* bc2 = (const float*)d_in[8];
    float* out = (float*)d_out;

    char* ws = (char*)d_ws;
    unsigned short* xb   = (unsigned short*)(ws);                  // 0..64 MB  bf16 x (later: weighted)
    unsigned short* W1t  = (unsigned short*)(ws + (64ll  << 20));  // 64..72
    unsigned short* Tb   = (unsigned short*)(ws + (72ll  << 20));  // 72..88
    unsigned short* W2t  = (unsigned short*)(ws + (88ll  << 20));  // 88..96
    unsigned short* abf  = (unsigned short*)(ws + (96ll  << 20));  // 96..160  a bf16
    float*          P3   = (float*)         (ws + (96ll  << 20));  // 96..128  GEMM3 partials (after abf dead)
    unsigned short* Wc1t = (unsigned short*)(ws + (160ll << 20));  // 160..161
    unsigned short* wb   = xb;

    // merged prep: x cvt + W1/W2/Wc1 transposes in one dispatch
    k_prep<<<41472, 256, 0, stream>>>(x, xb, W1, W1t, W2, W2t, Wc1, Wc1t);

    // T = tanh(x @ W1 + b1)  [8192][1024] bf16 — XCD-swizzled, BK=64
    k_gemm_tanh<<<512, 512, 0, stream>>>(xb, W1t, b1, Tb, 1024, 4096, 4096, 4096);
    // a = T @ W2 + b2  [8192][4096] bf16 — 256² 8-phase (32 bm x 16 bn tiles, LBN=4)
    k_gemm256<4><<<512, 512, 0, stream>>>(Tb, W2t, b2, abf, 4096, 1024, 1024, 1024);
    // weighted = x * sparsemax(a) -> bf16 (in place over xb)
    k_sparsemax<<<2048, 256, 0, stream>>>(abf, xb, wb);
    // GEMM3 split-K=8: P3[kz] = weighted @ Wc1 (unique reads; no swizzle needed)
    k_gemm<2, -1><<<dim3(1, 64, 8), 256, 0, stream>>>(wb, Wc1t, nullptr, P3, 128,
                                                      4096, 4096, 512, (size_t)8192 * 128);
    // out = relu(sum P3 + bc1) @ Wc2 + bc2
    k_final<<<2048, 256, 0, stream>>>(P3, bc1, Wc2, bc2, out);
}

// Round 8
// 432.650 us; speedup vs baseline: 1.1640x; 1.0022x over previous
//
#include <hip/hip_runtime.h>
#include <cstdint>

// ---------- common helpers ----------

typedef __bf16 bf16x8 __attribute__((ext_vector_type(8)));
typedef float  f32x4  __attribute__((ext_vector_type(4)));
typedef unsigned short u16x8 __attribute__((ext_vector_type(8)));

__device__ __forceinline__ unsigned short f2b(float f) {
    union { float f; unsigned u; } v; v.f = f;
    unsigned r = v.u + 0x7FFFu + ((v.u >> 16) & 1u);   // RNE
    return (unsigned short)(r >> 16);
}

__device__ __forceinline__ float b2f(unsigned short u) {
    union { unsigned u; float f; } v; v.u = ((unsigned)u) << 16;
    return v.f;
}

__device__ __forceinline__ float fast_tanh(float x) {
    // tanh(x) = 1 - 2/(e^{2x}+1); e^{2x} = 2^(x*2*log2 e). err ~1e-6 << bf16 eps
    float e = __builtin_amdgcn_exp2f(2.885390082f * x);
    return 1.0f - 2.0f * __builtin_amdgcn_rcpf(e + 1.0f);
}

__device__ __forceinline__ void async_copy16(void* lds, const void* g) {
    __builtin_amdgcn_global_load_lds(
        (const __attribute__((address_space(1))) unsigned int*)g,
        (__attribute__((address_space(3))) unsigned int*)lds,
        16, 0, 0);
}

// LDS layout (BK=64): tiles stored as 16B chunks; slot q (linear) holds global
// chunk (r=q>>3, c=(q&7)^(r&7)).
// => global chunk (r,c) lives at elem offset r*64 + ((c^(r&7))<<3).
// ds_read banks: addr/4 = 32r + 4(c^(r&7)) -> 2-way max (free, m136).

// ---------- merged prep: x->bf16 cvt + 3 weight transposes, ONE dispatch ----------
// blocks [0,32768): cvt x (float4->ushort4)
// blocks [32768,36864): W1 [4096][1024] -> W1t
// blocks [36864,40960): W2 [1024][4096] -> W2t
// blocks [40960,41472): Wc1 [4096][128] -> Wc1t

__global__ __launch_bounds__(256)
void k_prep(const float* __restrict__ x, unsigned short* __restrict__ xb,
            const float* __restrict__ W1, unsigned short* __restrict__ W1t,
            const float* __restrict__ W2, unsigned short* __restrict__ W2t,
            const float* __restrict__ Wc1, unsigned short* __restrict__ Wc1t) {
    const int b = blockIdx.x;
    if (b < 32768) {
        int i = b * 256 + threadIdx.x;
        float4 f = ((const float4*)x)[i];
        ((ushort4*)xb)[i] = make_ushort4(f2b(f.x), f2b(f.y), f2b(f.z), f2b(f.w));
        return;
    }
    const float* in; unsigned short* out; int R, C, rb;
    if (b < 36864)      { in = W1;  out = W1t;  R = 4096; C = 1024; rb = b - 32768; }
    else if (b < 40960) { in = W2;  out = W2t;  R = 1024; C = 4096; rb = b - 36864; }
    else                { in = Wc1; out = Wc1t; R = 4096; C = 128;  rb = b - 40960; }
    const int nbx = C >> 5;
    const int bc = (rb % nbx) * 32, br = (rb / nbx) * 32;
    const int tx = threadIdx.x & 31, ty = threadIdx.x >> 5;   // (32, 8)
    __shared__ float tile[32][33];
    #pragma unroll
    for (int i = 0; i < 32; i += 8)
        tile[ty + i][tx] = in[(size_t)(br + ty + i) * C + bc + tx];
    __syncthreads();
    #pragma unroll
    for (int i = 0; i < 32; i += 8)
        out[(size_t)(bc + ty + i) * R + br + tx] = f2b(tile[tx][ty + i]);
}

// ---------- GEMM1: 512-thread 128x128 tile, BK=64, bias+tanh -> bf16 ----------
// XCD-swizzled 1-D grid: bm % 8 == xcd. 8 waves, wave tile 64x32.
// Best-measured structure for this shape (r1/r7: ~76us, MfmaUtil ~36%).

__global__ __launch_bounds__(512, 4)
void k_gemm_tanh(const unsigned short* __restrict__ A,
                 const unsigned short* __restrict__ B,
                 const float* __restrict__ bias,
                 unsigned short* __restrict__ Out, int ldout,
                 int lda, int ldb, int k_len) {
    __shared__ __align__(16) unsigned short As[128 * 64];
    __shared__ __align__(16) unsigned short Bs[128 * 64];

    const int tid  = threadIdx.x;
    const int wave = tid >> 6;      // 0..7
    const int lane = tid & 63;
    const int quad = lane >> 4;
    const int l16  = lane & 15;
    const int wr   = wave >> 2;     // 0..1 : 64-row half
    const int wc   = wave & 3;      // 0..3 : 32-col quarter

    const int bid = blockIdx.x;
    const int xcd = bid & 7;
    const int lid = bid >> 3;
    const int bn  = lid & 7;
    const int bm  = (lid >> 3) * 8 + xcd;

    const unsigned short* Ag = A + (size_t)(bm * 128) * lda;
    const unsigned short* Bg = B + (size_t)(bn * 128) * ldb;

    f32x4 acc[4][2];
    #pragma unroll
    for (int i = 0; i < 4; i++)
        #pragma unroll
        for (int j = 0; j < 2; j++)
            acc[i][j] = f32x4{0.f, 0.f, 0.f, 0.f};

    // staging: 1024 chunks per matrix, 512 threads -> 2 issues each
    int sr[2], sc[2];
    #pragma unroll
    for (int j = 0; j < 2; j++) {
        int q = j * 512 + wave * 64 + lane;
        sr[j] = q >> 3;
        sc[j] = ((q & 7) ^ (sr[j] & 7)) << 3;   // element offset of source chunk
    }

    // fragment read offsets (loop-invariant)
    int roA[4], coA[4], roB[2], coB[2];
    #pragma unroll
    for (int i = 0; i < 4; i++) {
        int r = wr * 64 + i * 16 + l16;
        roA[i] = r * 64; coA[i] = quad ^ (r & 7);
    }
    #pragma unroll
    for (int j = 0; j < 2; j++) {
        int r = wc * 32 + j * 16 + l16;
        roB[j] = r * 64; coB[j] = quad ^ (r & 7);
    }

    for (int k0 = 0; k0 < k_len; k0 += 64) {
        #pragma unroll
        for (int j = 0; j < 2; j++) {
            async_copy16(&As[(j * 512 + wave * 64) * 8], Ag + (size_t)sr[j] * lda + k0 + sc[j]);
            async_copy16(&Bs[(j * 512 + wave * 64) * 8], Bg + (size_t)sr[j] * ldb + k0 + sc[j]);
        }
        asm volatile("s_waitcnt vmcnt(0)" ::: "memory");
        __syncthreads();

        #pragma unroll
        for (int s = 0; s < 2; s++) {
            bf16x8 av[4], bv[2];
            #pragma unroll
            for (int i = 0; i < 4; i++)
                av[i] = *(const bf16x8*)&As[roA[i] + ((coA[i] ^ (s << 2)) << 3)];
            #pragma unroll
            for (int j = 0; j < 2; j++)
                bv[j] = *(const bf16x8*)&Bs[roB[j] + ((coB[j] ^ (s << 2)) << 3)];
            #pragma unroll
            for (int i = 0; i < 4; i++)
                #pragma unroll
                for (int j = 0; j < 2; j++)
                    acc[i][j] = __builtin_amdgcn_mfma_f32_16x16x32_bf16(av[i], bv[j], acc[i][j], 0, 0, 0);
        }
        __syncthreads();
    }

    #pragma unroll
    for (int i = 0; i < 4; i++) {
        int rbase = bm * 128 + wr * 64 + i * 16 + quad * 4;
        #pragma unroll
        for (int j = 0; j < 2; j++) {
            int col = bn * 128 + wc * 32 + j * 16 + l16;
            float bc = bias[col];
            #pragma unroll
            for (int r = 0; r < 4; r++)
                Out[(size_t)(rbase + r) * ldout + col] = f2b(fast_tanh(acc[i][j][r] + bc));
        }
    }
}

// ---------- GEMM2: 256x256 tile, BK=64, 8-phase counted-vmcnt (r1 frozen) ----------

template <int LBN>
__global__ __launch_bounds__(512, 2)
void k_gemm256(const unsigned short* __restrict__ A,
               const unsigned short* __restrict__ B,
               const float* __restrict__ bias,
               unsigned short* __restrict__ Out, int ldout,
               int lda, int ldb, int k_len) {
    __shared__ __align__(16) unsigned short As[2][256 * 64];
    __shared__ __align__(16) unsigned short Bs[2][256 * 64];

    const int tid  = threadIdx.x;
    const int wave = tid >> 6;
    const int lane = tid & 63;
    const int quad = lane >> 4;
    const int l16  = lane & 15;
    const int wm   = wave >> 2;     // 0..1
    const int wn   = wave & 3;      // 0..3

    const int bid = blockIdx.x;
    const int xcd = bid & 7;
    const int lid = bid >> 3;
    const int bn  = lid & ((1 << LBN) - 1);
    const int bm  = (lid >> LBN) * 8 + xcd;

    const unsigned short* Ag = A + (size_t)(bm * 256) * lda;
    const unsigned short* Bg = B + (size_t)(bn * 256) * ldb;

    // staging per-thread constants (chunk q = u*512 + tid; lds row = u*64 + rr)
    const int rr = tid >> 3;
    const int sc = ((tid & 7) ^ (rr & 7)) << 3;
    int gA[4], gB[4];
    #pragma unroll
    for (int u = 0; u < 4; u++) {
        gA[u] = (u & 1) * 128 + (u >> 1) * 64 + rr;
        gB[u] = ((u & 1) * 2 + (rr >> 5)) * 64 + (u >> 1) * 32 + (rr & 31);
    }

    // fragment read offsets: lds rows per permuted layout; lr&7 == l16&7 always
    const int co = quad ^ (l16 & 7);
    int baseA[8], baseB[4];
    #pragma unroll
    for (int i = 0; i < 8; i++)
        baseA[i] = ((i >> 2) * 128 + wm * 64 + (i & 3) * 16 + l16) * 64;
    #pragma unroll
    for (int j = 0; j < 4; j++)
        baseB[j] = ((j >> 1) * 128 + wn * 32 + (j & 1) * 16 + l16) * 64;

    f32x4 acc[8][4];
    #pragma unroll
    for (int i = 0; i < 8; i++)
        #pragma unroll
        for (int j = 0; j < 4; j++)
            acc[i][j] = f32x4{0.f, 0.f, 0.f, 0.f};

    bf16x8 avq[2][4], bvA[2][2], bvB[2][2];

    auto stageA2 = [&](int buf, int u0, int k0) {
        #pragma unroll
        for (int d = 0; d < 2; d++) {
            int u = u0 + d;
            async_copy16(&As[buf][(u * 512 + wave * 64) * 8],
                         Ag + (size_t)gA[u] * lda + k0 + sc);
        }
    };
    auto stageB2 = [&](int buf, int u0, int k0) {
        #pragma unroll
        for (int d = 0; d < 2; d++) {
            int u = u0 + d;
            async_copy16(&Bs[buf][(u * 512 + wave * 64) * 8],
                         Bg + (size_t)gB[u] * ldb + k0 + sc);
        }
    };
    auto readA = [&](int buf, int mh) {
        #pragma unroll
        for (int s = 0; s < 2; s++)
            #pragma unroll
            for (int i = 0; i < 4; i++)
                avq[s][i] = *(const bf16x8*)&As[buf][baseA[mh * 4 + i] + ((co ^ (s << 2)) << 3)];
    };
    auto readB = [&](int buf, int nh, bf16x8 (&bv)[2][2]) {
        #pragma unroll
        for (int s = 0; s < 2; s++)
            #pragma unroll
            for (int j = 0; j < 2; j++)
                bv[s][j] = *(const bf16x8*)&Bs[buf][baseB[nh * 2 + j] + ((co ^ (s << 2)) << 3)];
    };
    auto mmaQ = [&](int mh, int nh, bf16x8 (&bv)[2][2]) {
        __builtin_amdgcn_s_setprio(1);
        #pragma unroll
        for (int s = 0; s < 2; s++)
            #pragma unroll
            for (int i = 0; i < 4; i++)
                #pragma unroll
                for (int j = 0; j < 2; j++)
                    acc[mh * 4 + i][nh * 2 + j] = __builtin_amdgcn_mfma_f32_16x16x32_bf16(
                        avq[s][i], bv[s][j], acc[mh * 4 + i][nh * 2 + j], 0, 0, 0);
        __builtin_amdgcn_s_setprio(0);
    };

    auto tile = [&](int rb, int k0n) {
        const int sb = rb ^ 1;
        // phase 1: quadrant (mh0, nh0)
        readA(rb, 0); readB(rb, 0, bvA);
        stageA2(sb, 0, k0n);
        asm volatile("s_waitcnt vmcnt(4)" ::: "memory");
        asm volatile("s_barrier" ::: "memory");
        mmaQ(0, 0, bvA);
        asm volatile("s_barrier" ::: "memory");
        // phase 2: quadrant (mh0, nh1)
        readB(rb, 1, bvB);
        stageB2(sb, 0, k0n);
        asm volatile("s_waitcnt vmcnt(4)" ::: "memory");
        asm volatile("s_barrier" ::: "memory");
        mmaQ(0, 1, bvB);
        asm volatile("s_barrier" ::: "memory");
        // phase 3: quadrant (mh1, nh1)
        readA(rb, 1);
        stageB2(sb, 2, k0n);
        asm volatile("s_waitcnt vmcnt(4)" ::: "memory");
        asm volatile("s_barrier" ::: "memory");
        mmaQ(1, 1, bvB);
        asm volatile("s_barrier" ::: "memory");
        // phase 4: quadrant (mh1, nh0) — bvA still live from phase 1
        stageA2(sb, 2, k0n);
        asm volatile("s_waitcnt vmcnt(4)" ::: "memory");
        asm volatile("s_barrier" ::: "memory");
        mmaQ(1, 0, bvA);
        asm volatile("s_barrier" ::: "memory");
    };

    // prologue: stage tile 0 in steady-state order A01, B01, B23, A23
    stageA2(0, 0, 0);
    stageB2(0, 0, 0);
    stageB2(0, 2, 0);
    stageA2(0, 2, 0);
    asm volatile("s_waitcnt vmcnt(4)" ::: "memory");
    asm volatile("s_barrier" ::: "memory");

    const int NT = k_len >> 6;   // must be even
    for (int kt = 0; kt < NT; kt += 2) {
        int k1 = (kt + 1) * 64;
        int k2 = (kt + 2 < NT ? kt + 2 : 0) * 64;   // wrap: tail loads harmless
        tile(0, k1);
        tile(1, k2);
    }

    #pragma unroll
    for (int i = 0; i < 8; i++) {
        int rbase = bm * 256 + wm * 128 + i * 16 + quad * 4;
        #pragma unroll
        for (int j = 0; j < 4; j++) {
            int col = bn * 256 + wn * 64 + j * 16 + l16;
            float bc = bias[col];
            #pragma unroll
            for (int r = 0; r < 4; r++)
                Out[(size_t)(rbase + r) * ldout + col] = f2b(acc[i][j][r] + bc);
        }
    }
}

// ---------- 256-thread 128x128 GEMM, BK=64 ----------
// MODE 2: store fp32 partial at Out + kz*pstride (split-K, 3-D grid)

template <int MODE, int LBN>
__global__ __launch_bounds__(256, 3)
void k_gemm(const unsigned short* __restrict__ A,
            const unsigned short* __restrict__ B,
            const float* __restrict__ bias,
            void* __restrict__ Out, int ldout,
            int lda, int ldb, int k_len, size_t pstride) {
    __shared__ __align__(16) unsigned short As[128 * 64];
    __shared__ __align__(16) unsigned short Bs[128 * 64];

    const int tid  = threadIdx.x;
    const int wave = tid >> 6;
    const int lane = tid & 63;
    const int quad = lane >> 4;
    const int l16  = lane & 15;
    const int wr   = wave >> 1;
    const int wc   = wave & 1;

    int bn, bm, kz;
    if (LBN >= 0) {
        const int bid = blockIdx.x;
        const int xcd = bid & 7;
        const int lid = bid >> 3;
        bn = lid & ((1 << LBN) - 1);
        bm = (lid >> LBN) * 8 + xcd;    // bm % 8 == xcd
        kz = 0;
    } else {
        bn = blockIdx.x; bm = blockIdx.y; kz = blockIdx.z;
    }

    const unsigned short* Ag = A + (size_t)(bm * 128) * lda + (size_t)kz * k_len;
    const unsigned short* Bg = B + (size_t)(bn * 128) * ldb + (size_t)kz * k_len;

    f32x4 acc[4][4];
    #pragma unroll
    for (int i = 0; i < 4; i++)
        #pragma unroll
        for (int j = 0; j < 4; j++)
            acc[i][j] = f32x4{0.f, 0.f, 0.f, 0.f};

    // staging: 1024 chunks per matrix, 256 threads -> 4 issues each
    int sr[4], sc[4];
    #pragma unroll
    for (int j = 0; j < 4; j++) {
        int q = j * 256 + wave * 64 + lane;
        sr[j] = q >> 3;
        sc[j] = ((q & 7) ^ (sr[j] & 7)) << 3;
    }

    int roA[4], coA[4], roB[4], coB[4];
    #pragma unroll
    for (int i = 0; i < 4; i++) {
        int ra = wr * 64 + i * 16 + l16;
        roA[i] = ra * 64; coA[i] = quad ^ (ra & 7);
        int rb = wc * 64 + i * 16 + l16;
        roB[i] = rb * 64; coB[i] = quad ^ (rb & 7);
    }

    for (int k0 = 0; k0 < k_len; k0 += 64) {
        #pragma unroll
        for (int j = 0; j < 4; j++) {
            async_copy16(&As[(j * 256 + wave * 64) * 8], Ag + (size_t)sr[j] * lda + k0 + sc[j]);
            async_copy16(&Bs[(j * 256 + wave * 64) * 8], Bg + (size_t)sr[j] * ldb + k0 + sc[j]);
        }
        asm volatile("s_waitcnt vmcnt(0)" ::: "memory");
        __syncthreads();

        #pragma unroll
        for (int s = 0; s < 2; s++) {
            bf16x8 av[4], bv[4];
            #pragma unroll
            for (int i = 0; i < 4; i++)
                av[i] = *(const bf16x8*)&As[roA[i] + ((coA[i] ^ (s << 2)) << 3)];
            #pragma unroll
            for (int j = 0; j < 4; j++)
                bv[j] = *(const bf16x8*)&Bs[roB[j] + ((coB[j] ^ (s << 2)) << 3)];
            #pragma unroll
            for (int i = 0; i < 4; i++)
                #pragma unroll
                for (int j = 0; j < 4; j++)
                    acc[i][j] = __builtin_amdgcn_mfma_f32_16x16x32_bf16(av[i], bv[j], acc[i][j], 0, 0, 0);
        }
        __syncthreads();
    }

    #pragma unroll
    for (int i = 0; i < 4; i++) {
        int rbase = bm * 128 + wr * 64 + i * 16 + quad * 4;
        #pragma unroll
        for (int j = 0; j < 4; j++) {
            int col = bn * 128 + wc * 64 + j * 16 + l16;
            #pragma unroll
            for (int r = 0; r < 4; r++) {
                int row = rbase + r;
                float val = acc[i][j][r];
                if (MODE == 1) {
                    val += bias[col];
                    ((unsigned short*)Out)[(size_t)row * ldout + col] = f2b(val);
                } else {
                    ((float*)Out)[kz * pstride + (size_t)row * ldout + col] = val;
                }
            }
        }
    }
}

// ---------- sparsemax + gating: one WAVE per row, zero barriers ----------
__global__ __launch_bounds__(256)
void k_sparsemax(const unsigned short* __restrict__ a,
                 const unsigned short* __restrict__ xb,
                 unsigned short* __restrict__ wout) {
    const int wave = threadIdx.x >> 6;
    const int lane = threadIdx.x & 63;
    const int row = blockIdx.x * 4 + wave;

    const u16x8* ar = (const u16x8*)(a + (size_t)row * 4096);
    float v[64];
    #pragma unroll
    for (int j = 0; j < 8; j++) {
        u16x8 u = ar[lane + 64 * j];
        #pragma unroll
        for (int k = 0; k < 8; k++) v[j * 8 + k] = b2f(u[k]);
    }

    float m = v[0];
    #pragma unroll
    for (int i = 1; i < 64; i++) m = fmaxf(m, v[i]);
    #pragma unroll
    for (int off = 1; off < 64; off <<= 1) m = fmaxf(m, __shfl_xor(m, off));

    float lo = m - 1.0f, hi = m;
    #pragma unroll 1
    for (int it = 0; it < 14; ++it) {
        float mid = 0.5f * (lo + hi);
        float s = 0.f;
        #pragma unroll
        for (int i = 0; i < 64; i++) s += fmaxf(v[i] - mid, 0.f);
        #pragma unroll
        for (int off = 1; off < 64; off <<= 1) s += __shfl_xor(s, off);
        if (s > 1.0f) lo = mid; else hi = mid;
    }
    float tau = 0.5f * (lo + hi);

    const u16x8* xr = (const u16x8*)(xb + (size_t)row * 4096);
    u16x8* wr_ = (u16x8*)(wout + (size_t)row * 4096);
    #pragma unroll
    for (int j = 0; j < 8; j++) {
        u16x8 xv = xr[lane + 64 * j];
        u16x8 o;
        #pragma unroll
        for (int k = 0; k < 8; k++)
            o[k] = f2b(fmaxf(v[j * 8 + k] - tau, 0.f) * b2f(xv[k]));
        wr_[lane + 64 * j] = o;
    }
}

// ---------- final: out = relu(sum_p P[p] + bc1) @ Wc2 + bc2 ----------
__global__ __launch_bounds__(256)
void k_final(const float* __restrict__ P, const float* __restrict__ bc1,
             const float* __restrict__ Wc2, const float* __restrict__ bc2,
             float* __restrict__ out) {
    __shared__ float w2s[128 * 16];
    __shared__ float hs[4 * 128];
    const int tid = threadIdx.x;
    for (int i = tid; i < 2048; i += 256) w2s[i] = Wc2[i];

    #pragma unroll
    for (int i = tid; i < 512; i += 256) {
        int r = i >> 7, c = i & 127;
        int row = blockIdx.x * 4 + r;
        float s = bc1[c];
        #pragma unroll
        for (int p = 0; p < 4; p++)
            s += P[((size_t)p * 8192 + row) * 128 + c];
        hs[i] = fmaxf(s, 0.f);
    }
    __syncthreads();

    const int wave = tid >> 6, lane = tid & 63;
    const int row = blockIdx.x * 4 + wave;
    const int c = lane & 15, hq = lane >> 4;
    float acc = 0.f;
    #pragma unroll
    for (int t = 0; t < 32; ++t) {
        int hidx = hq * 32 + t;
        acc += hs[wave * 128 + hidx] * w2s[hidx * 16 + c];
    }
    acc += __shfl_xor(acc, 16);
    acc += __shfl_xor(acc, 32);
    if (hq == 0) out[(size_t)row * 16 + c] = acc + bc2[c];
}

// ---------- launch ----------

extern "C" void kernel_launch(void* const* d_in, const int* in_sizes, int n_in,
                              void* d_out, int out_size, void* d_ws, size_t ws_size,
                              hipStream_t stream) {
    (void)in_sizes; (void)n_in; (void)out_size; (void)ws_size;
    const float* x   = (const float*)d_in[0];
    const float* W1  = (const float*)d_in[1];
    const float* b1  = (const float*)d_in[2];
    const float* W2  = (const float*)d_in[3];
    const float* b2  = (const float*)d_in[4];
    const float* Wc1 = (const float*)d_in[5];
    const float* bc1 = (const float*)d_in[6];
    const float* Wc2 = (const float*)d_in[7];
    const float* bc2 = (const float*)d_in[8];
    float* out = (float*)d_out;

    char* ws = (char*)d_ws;
    unsigned short* xb   = (unsigned short*)(ws);                  // 0..64 MB  bf16 x (later: weighted)
    unsigned short* W1t  = (unsigned short*)(ws + (64ll  << 20));  // 64..72
    unsigned short* Tb   = (unsigned short*)(ws + (72ll  << 20));  // 72..88
    unsigned short* W2t  = (unsigned short*)(ws + (88ll  << 20));  // 88..96
    unsigned short* abf  = (unsigned short*)(ws + (96ll  << 20));  // 96..160  a bf16
    float*          P3   = (float*)         (ws + (96ll  << 20));  // 96..112  GEMM3 partials (after abf dead; split-K=4)
    unsigned short* Wc1t = (unsigned short*)(ws + (160ll << 20));  // 160..161
    unsigned short* wb   = xb;

    // merged prep: x cvt + W1/W2/Wc1 transposes in one dispatch
    k_prep<<<41472, 256, 0, stream>>>(x, xb, W1, W1t, W2, W2t, Wc1, Wc1t);

    // T = tanh(x @ W1 + b1)  [8192][1024] bf16 — XCD-swizzled, BK=64
    k_gemm_tanh<<<512, 512, 0, stream>>>(xb, W1t, b1, Tb, 1024, 4096, 4096, 4096);
    // a = T @ W2 + b2  [8192][4096] bf16 — 256² 8-phase (32 bm x 16 bn tiles, LBN=4)
    k_gemm256<4><<<512, 512, 0, stream>>>(Tb, W2t, b2, abf, 4096, 1024, 1024, 1024);
    // weighted = x * sparsemax(a) -> bf16 (in place over xb)
    k_sparsemax<<<2048, 256, 0, stream>>>(abf, xb, wb);
    // GEMM3 split-K=4: P3[kz] = weighted @ Wc1 (256 blocks = 1/CU; halves partial traffic)
    k_gemm<2, -1><<<dim3(1, 64, 4), 256, 0, stream>>>(wb, Wc1t, nullptr, P3, 128,
                                                      4096, 4096, 1024, (size_t)8192 * 128);
    // out = relu(sum P3 + bc1) @ Wc2 + bc2
    k_final<<<2048, 256, 0, stream>>>(P3, bc1, Wc2, bc2, out);
}